// Round 5
// baseline (1060.494 us; speedup 1.0000x reference)
//
#include <hip/hip_runtime.h>

typedef unsigned short u16;
typedef unsigned int   u32;

__device__ __forceinline__ u16 f2bf(float f){
  u32 u = __float_as_uint(f);
  return (u16)((u + 0x7FFFu + ((u >> 16) & 1u)) >> 16);  // RNE
}
__device__ __forceinline__ float bf2f(u16 h){ return __uint_as_float(((u32)h) << 16); }

// Fully fused CLLA path: per block = 20 coarse pixels (one quarter of a coarse row).
// LDS layout (51,520 B total):
//   f2s  float[128][20] @ 0       (10240)
//   qs   float[128][20] @ 10240   (10240)  -> reused as gs
//   rs   float[128][20] @ 20480   (10240)  -> reused as fs
//   f1s  u16  [128][80] @ 30720   (20480)  (transiently x1s float[256][20])
//   atts float[20][4]   @ 51200   (320)
__global__ __launch_bounds__(256) void fused_k(
    const float* __restrict__ x0, const float* __restrict__ x1,
    const float* __restrict__ wc1, const float* __restrict__ bc1,
    const float* __restrict__ wc2, const float* __restrict__ bc2,
    const float* __restrict__ wq,  const float* __restrict__ bq,
    const float* __restrict__ wk,  const float* __restrict__ bk,
    const float* __restrict__ wv,  const float* __restrict__ bv,
    const float* __restrict__ wdet, const float* __restrict__ bdet,
    float* __restrict__ out)
{
  __shared__ char smem[51520];
  float* f2s = (float*)smem;             // [128][20]
  float* qs  = (float*)(smem + 10240);   // [128][20], later gs
  float* rs  = (float*)(smem + 20480);   // [128][20], later fs
  u16*   f1s = (u16*)  (smem + 30720);   // [128][80]
  float* x1s = (float*)(smem + 30720);   // [256][20] transient
  float* atts= (float*)(smem + 51200);   // [20][4]

  const int t   = threadIdx.x;
  const int blk = blockIdx.x;
  const int b   = blk / 320, rem = blk % 320;
  const int h   = rem >> 2, wb = (rem & 3) * 20;   // coarse row h, cols [wb, wb+20)

  const int co  = t >> 1;          // output channel for matvec phases
  const int hf  = t & 1;           // which half of the pixel range
  const int h10 = hf * 10;

  // ---- P0: stage x1 slice [256][20] ----
  {
    const float* xp = x1 + (size_t)b * 256 * 6400 + h * 80 + wb;
    #pragma unroll
    for (int rep = 0; rep < 20; rep++){
      int idx = rep * 256 + t;
      int ci = idx / 20, wl = idx % 20;
      x1s[ci * 20 + wl] = xp[(size_t)ci * 6400 + wl];
    }
  }
  __syncthreads();

  // ---- P1: f2 = Wc2 @ x1 + bc2 ----
  {
    float acc[10];
    #pragma unroll
    for (int j = 0; j < 10; j++) acc[j] = bc2[co];
    for (int ci = 0; ci < 256; ci++){
      float w = wc2[co * 256 + ci];
      #pragma unroll
      for (int j = 0; j < 10; j++) acc[j] += w * x1s[ci * 20 + h10 + j];
    }
    #pragma unroll
    for (int j = 0; j < 10; j++) f2s[co * 20 + h10 + j] = acc[j];
  }
  __syncthreads();

  // ---- P2: q = Wq @ f2 + bq ----
  {
    float acc[10];
    #pragma unroll
    for (int j = 0; j < 10; j++) acc[j] = bq[co];
    for (int ci = 0; ci < 128; ci++){
      float w = wq[co * 128 + ci];
      #pragma unroll
      for (int j = 0; j < 10; j++) acc[j] += w * f2s[ci * 20 + h10 + j];
    }
    #pragma unroll
    for (int j = 0; j < 10; j++) qs[co * 20 + h10 + j] = acc[j];
  }
  __syncthreads();

  // ---- P3: r = 0.5 * Wk^T @ q  (dots_n = r . f1_n + const; const cancels in softmax) ----
  {
    float acc[10];
    #pragma unroll
    for (int j = 0; j < 10; j++) acc[j] = 0.f;
    for (int ci = 0; ci < 128; ci++){
      float w = wk[ci * 128 + co];        // Wk^T
      #pragma unroll
      for (int j = 0; j < 10; j++) acc[j] += w * qs[ci * 20 + h10 + j];
    }
    #pragma unroll
    for (int j = 0; j < 10; j++) rs[co * 20 + h10 + j] = 0.5f * acc[j];
  }
  __syncthreads();

  // ---- P4: f1 = Wc1 @ x0 + bc1 over 80 fine pixels (2 rows x 40 cols), bf16 in LDS ----
  {
    float acc[40];
    #pragma unroll
    for (int j = 0; j < 40; j++) acc[j] = bc1[co];
    const float* x0p = x0 + (size_t)b * 128 * 25600 + (2 * h) * 160 + 2 * wb + hf * 160;
    for (int ci = 0; ci < 128; ci++){
      float w = wc1[co * 128 + ci];
      const float* xr = x0p + (size_t)ci * 25600;
      #pragma unroll
      for (int j = 0; j < 40; j++) acc[j] += w * xr[j];
    }
    #pragma unroll
    for (int j = 0; j < 40; j++) f1s[co * 80 + hf * 40 + j] = f2bf(acc[j]);
  }
  __syncthreads();

  // ---- P5: dots + softmax (4 threads per coarse pixel) ----
  if (t < 80){
    const int wl = t >> 2, n = t & 3;
    const int fp = (n >> 1) * 40 + wl * 2 + (n & 1);
    float d = 0.f;
    for (int ci = 0; ci < 128; ci++) d += rs[ci * 20 + wl] * bf2f(f1s[ci * 80 + fp]);
    float s = d + __shfl_xor(d, 1); s += __shfl_xor(s, 2);
    float irr = 0.5f * s - d;                       // 2*mean - dot (+const, cancels)
    float mx = fmaxf(irr, __shfl_xor(irr, 1)); mx = fmaxf(mx, __shfl_xor(mx, 2));
    float e = __expf(irr - mx);
    float den = e + __shfl_xor(e, 1); den += __shfl_xor(den, 2);
    atts[wl * 4 + n] = e / den;
  }
  __syncthreads();

  // ---- P6a: g = sum_n att_n * f1_n  (into qs) ----
  {
    #pragma unroll
    for (int j = 0; j < 10; j++){
      int wl = h10 + j;
      float g = 0.f;
      #pragma unroll
      for (int n = 0; n < 4; n++){
        int fp = (n >> 1) * 40 + wl * 2 + (n & 1);
        g += atts[wl * 4 + n] * bf2f(f1s[co * 80 + fp]);
      }
      qs[co * 20 + wl] = g;
    }
  }
  __syncthreads();

  // ---- P6b: f = 0.5*(Wv @ g + bv + f2)  (into rs) ----
  {
    float acc[10];
    #pragma unroll
    for (int j = 0; j < 10; j++) acc[j] = bv[co];
    for (int ci = 0; ci < 128; ci++){
      float w = wv[co * 128 + ci];
      #pragma unroll
      for (int j = 0; j < 10; j++) acc[j] += w * qs[ci * 20 + h10 + j];
    }
    #pragma unroll
    for (int j = 0; j < 10; j++)
      rs[co * 20 + h10 + j] = 0.5f * (acc[j] + f2s[co * 20 + h10 + j]);
  }
  __syncthreads();

  // ---- P7: p0 = Wdet @ f + bdet, det-head permuted write (fp32 out) ----
  if (t < 255){
    const int oc = t, a = oc / 85, o = oc % 85;
    float acc[20];
    #pragma unroll
    for (int j = 0; j < 20; j++) acc[j] = bdet[oc];
    for (int ci = 0; ci < 128; ci++){
      float w = wdet[oc * 128 + ci];
      #pragma unroll
      for (int j = 0; j < 20; j++) acc[j] += w * rs[ci * 20 + j];
    }
    size_t base = ((size_t)(b * 3 + a) * 6400 + h * 80 + wb) * 85 + o;
    #pragma unroll
    for (int j = 0; j < 20; j++) out[base + (size_t)j * 85] = acc[j];
  }
}

// ---- p1/p2 heads: block computes P pixels; weights read once per block ----
template<int PPB, int K, int P>
__global__ __launch_bounds__(256) void head_k(const float* __restrict__ x,
                                              const float* __restrict__ wm,
                                              const float* __restrict__ bm,
                                              float* __restrict__ out, size_t off)
{
  __shared__ float xs[K * P];              // 32 KB for both instantiations
  const int t = threadIdx.x;
  const int gp0 = blockIdx.x * P;
  const int b = gp0 / PPB, p0 = gp0 % PPB;
  const float* xp = x + (size_t)b * K * PPB + p0;
  #pragma unroll
  for (int rep = 0; rep < K * P / 256; rep++){
    int idx = rep * 256 + t;
    int ci = idx / P, i = idx % P;
    xs[ci * P + i] = xp[(size_t)ci * PPB + i];
  }
  __syncthreads();
  if (t < 255){
    float acc[P];
    #pragma unroll
    for (int i = 0; i < P; i++) acc[i] = bm[t];
    for (int ci = 0; ci < K; ci++){
      float w = wm[t * K + ci];
      #pragma unroll
      for (int i = 0; i < P; i++) acc[i] += w * xs[ci * P + i];
    }
    const int a = t / 85, o = t % 85;
    size_t base = off + ((size_t)(b * 3 + a) * PPB + p0) * 85 + o;
    #pragma unroll
    for (int i = 0; i < P; i++) out[base + (size_t)i * 85] = acc[i];
  }
}

extern "C" void kernel_launch(void* const* d_in, const int* in_sizes, int n_in,
                              void* d_out, int out_size, void* d_ws, size_t ws_size,
                              hipStream_t stream)
{
  (void)in_sizes; (void)n_in; (void)out_size; (void)d_ws; (void)ws_size;
  const float* x0  = (const float*)d_in[0];
  const float* x1  = (const float*)d_in[1];
  const float* x2  = (const float*)d_in[2];
  const float* x3  = (const float*)d_in[3];
  const float* wc1 = (const float*)d_in[4];  const float* bc1 = (const float*)d_in[5];
  const float* wc2 = (const float*)d_in[6];  const float* bc2 = (const float*)d_in[7];
  const float* wq  = (const float*)d_in[8];  const float* bq  = (const float*)d_in[9];
  const float* wk  = (const float*)d_in[10]; const float* bk  = (const float*)d_in[11];
  const float* wv  = (const float*)d_in[12]; const float* bv  = (const float*)d_in[13];
  const float* wdt = (const float*)d_in[14]; const float* bdt = (const float*)d_in[15];
  const float* wm0 = (const float*)d_in[16]; const float* bm0 = (const float*)d_in[17];
  const float* wm1 = (const float*)d_in[18]; const float* bm1 = (const float*)d_in[19];
  float* out = (float*)d_out;

  fused_k<<<2560, 256, 0, stream>>>(x0, x1, wc1, bc1, wc2, bc2, wq, bq, wk, bk,
                                    wv, bv, wdt, bdt, out);
  head_k<1600, 512, 16><<<800, 256, 0, stream>>>(x2, wm0, bm0, out, 13056000UL);
  head_k<400, 1024, 8><<<400, 256, 0, stream>>>(x3, wm1, bm1, out, 16320000UL);
}

// Round 6
// 208.280 us; speedup vs baseline: 5.0917x; 5.0917x over previous
//
#include <hip/hip_runtime.h>

typedef unsigned short u16;
typedef unsigned int   u32;
typedef __bf16 bf16x8 __attribute__((ext_vector_type(8)));
typedef float  f32x4  __attribute__((ext_vector_type(4)));

__device__ __forceinline__ u16 f2bf(float f){
  u32 u = __float_as_uint(f);
  return (u16)((u + 0x7FFFu + ((u >> 16) & 1u)) >> 16);  // RNE
}
__device__ __forceinline__ float bf2f(u16 h){ return __uint_as_float(((u32)h) << 16); }

// ---------------- workspace layout (bytes) ----------------
#define WS_A1   0u          // A1 wimg [384][256] bf16 (BN=128,nK=4)   196608
#define WS_WM0  196608u     // Wm0 wimg [256][512]  (BN=256,nK=8)      262144
#define WS_WM1  458752u     // Wm1 wimg [256][1024] (BN=256,nK=16)     524288
#define WS_WC1  983040u     // Wc1 linear [128][128] bf16               32768
#define WS_WDV  1015808u    // Wdv=0.5*Wdet@Wv linear [256][128] bf16   65536
#define WS_C1   1081344u    // c1[384] f32 (fused bias of R)
#define WS_B2   1082880u    // b2[256] f32 (bdet + 0.5*Wdet*bv)
#define WS_BC1  1083904u    // bc1[128] f32
#define WS_BM0  1084416u    // [256] f32
#define WS_BM1  1085440u    // [256] f32
#define WS_T    1086464u    // T[128][256] f32 scratch (Wq@Wc2)
#define WS_U    1217536u    // u[128] f32 (Wq*bc2+bq)
#define WS_R    1218048u    // R[51200][384] bf16 = [r(128)|h0(255)|pad]
// end ~40.5 MB

// weight-image element address (round-2 validated layout: 128B rows per 64-k tile)
__device__ __forceinline__ size_t wimg_off(int n, int k, int BN, int nK){
  int nt = n / BN, r = n % BN, kt = k >> 6;
  int slot = (((k & 63) >> 3) ^ (r & 7));
  return (size_t)(nt * nK + kt) * (size_t)(BN * 128) + (size_t)r * 128 + (slot << 4) + (k & 7) * 2;
}

// ---------------- prep1: T = Wq@Wc2, u = Wq*bc2+bq ----------------
__global__ __launch_bounds__(256) void prep1_k(const float* __restrict__ wq, const float* __restrict__ bq,
                                               const float* __restrict__ wc2, const float* __restrict__ bc2,
                                               char* ws)
{
  float* T = (float*)(ws + WS_T);
  float* u = (float*)(ws + WS_U);
  const int a = blockIdx.x, j = threadIdx.x;
  float s = 0.f;
  for (int c = 0; c < 128; c++) s += wq[a * 128 + c] * wc2[c * 256 + j];
  T[a * 256 + j] = s;
  if (j == 0){
    float su = bq[a];
    for (int c = 0; c < 128; c++) su += wq[a * 128 + c] * bc2[c];
    u[a] = su;
  }
}

// ---------------- prep2: all weight images + fused biases ----------------
__global__ __launch_bounds__(256) void prep2_k(
    const float* __restrict__ wc1, const float* __restrict__ bc1,
    const float* __restrict__ wc2, const float* __restrict__ bc2,
    const float* __restrict__ wk,  const float* __restrict__ wv, const float* __restrict__ bv,
    const float* __restrict__ wdet, const float* __restrict__ bdet,
    const float* __restrict__ wm0, const float* __restrict__ bm0,
    const float* __restrict__ wm1, const float* __restrict__ bm1,
    char* ws)
{
  const float* T = (const float*)(ws + WS_T);
  const float* u = (const float*)(ws + WS_U);
  int idx = blockIdx.x * 256 + threadIdx.x;
  if (idx < 98304){                       // A1 [384][256]: rows 0..127 = 0.5*Wk^T@T, 128..382 = 0.5*Wdet@Wc2
    int n = idx >> 8, k = idx & 255;
    float s = 0.f;
    if (n < 128){
      for (int a = 0; a < 128; a++) s += wk[a * 128 + n] * T[a * 256 + k];
      s *= 0.5f;
    } else if (n < 383){
      int oc = n - 128;
      for (int c = 0; c < 128; c++) s += wdet[oc * 128 + c] * wc2[c * 256 + k];
      s *= 0.5f;
    }
    *(u16*)(ws + WS_A1 + wimg_off(n, k, 128, 4)) = f2bf(s);
  } else if (idx < 98688){                // c1[384]
    int n = idx - 98304;
    float s = 0.f;
    if (n < 128){
      for (int a = 0; a < 128; a++) s += wk[a * 128 + n] * u[a];
      s *= 0.5f;
    } else if (n < 383){
      int oc = n - 128;
      for (int c = 0; c < 128; c++) s += wdet[oc * 128 + c] * bc2[c];
      s *= 0.5f;
    }
    ((float*)(ws + WS_C1))[n] = s;
  } else if (idx < 115072){               // Wc1 linear [128][128]
    int id = idx - 98688; int n = id >> 7, k = id & 127;
    ((u16*)(ws + WS_WC1))[n * 128 + k] = f2bf(wc1[n * 128 + k]);
  } else if (idx < 147840){               // Wdv = 0.5*Wdet@Wv linear [256][128]
    int id = idx - 115072; int n = id >> 7, k = id & 127;
    float s = 0.f;
    if (n < 255){
      for (int c = 0; c < 128; c++) s += wdet[n * 128 + c] * wv[c * 128 + k];
      s *= 0.5f;
    }
    ((u16*)(ws + WS_WDV))[n * 128 + k] = f2bf(s);
  } else if (idx < 148096){               // b2[256] = bdet + 0.5*Wdet*bv
    int n = idx - 147840;
    float s = 0.f;
    if (n < 255){
      float ss = 0.f;
      for (int c = 0; c < 128; c++) ss += wdet[n * 128 + c] * bv[c];
      s = bdet[n] + 0.5f * ss;
    }
    ((float*)(ws + WS_B2))[n] = s;
  } else if (idx < 148224){               // bc1 copy
    int n = idx - 148096; ((float*)(ws + WS_BC1))[n] = bc1[n];
  } else if (idx < 279296){               // Wm0 image [256][512]
    int id = idx - 148224; int n = id >> 9, k = id & 511;
    float s = (n < 255) ? wm0[n * 512 + k] : 0.f;
    *(u16*)(ws + WS_WM0 + wimg_off(n, k, 256, 8)) = f2bf(s);
  } else if (idx < 541440){               // Wm1 image [256][1024]
    int id = idx - 279296; int n = id >> 10, k = id & 1023;
    float s = (n < 255) ? wm1[n * 1024 + k] : 0.f;
    *(u16*)(ws + WS_WM1 + wimg_off(n, k, 256, 16)) = f2bf(s);
  } else if (idx < 541952){               // bm0f/bm1f
    int id = idx - 541440;
    if (id < 256) ((float*)(ws + WS_BM0))[id] = (id < 255) ? bm0[id] : 0.f;
    else { int n = id - 256; ((float*)(ws + WS_BM1))[n] = (n < 255) ? bm1[n] : 0.f; }
  }
}

// ---------------- generic MFMA GEMM (round-2 machinery, fp32 NCHW A, fp32 out for EPI=2) ----------------
// C[m][n] = sum_k A[m][k]*W[n][k] + bias[n]
// EPI 0: bf16 rows of ROWB bytes at outp ; EPI 2: fp32 det-head permute into d_out
template<int M, int Kd, int BM, int BN, int WM, int WN, int PPB, int Cin, int EPI, int ROWB>
__global__ __launch_bounds__(256) void gemm_k(const float* __restrict__ Ap, const char* __restrict__ wimg,
                                              const float* __restrict__ bias, void* __restrict__ outp, long out_off)
{
  constexpr int nK  = Kd / 64;
  constexpr int TPP = 256 / BM;
  constexpr int CPT = 64 / TPP;
  __shared__ char lds[BM * 128 + BN * 128];
  char* ldsA = lds;
  char* ldsW = lds + BM * 128;
  const int t = threadIdx.x;
  const int lane = t & 63;
  const int wid = t >> 6;
  const int wm = wid / WN, wn = wid % WN;
  const int nt = blockIdx.x, mt = blockIdx.y;
  const int m0 = mt * BM, n0 = nt * BN;
  const int lr = lane & 15, lg = lane >> 4;
  f32x4 acc[4][4] = {};

  const int pi = t % BM, cb = t / BM;
  const float* asrc;
  {
    int mg = m0 + pi; int b = mg / PPB; int p = mg - b * PPB;
    asrc = Ap + (size_t)b * Cin * PPB + p;
  }

  for (int kt = 0; kt < nK; kt++){
    {
      float tf[CPT];
      const float* sp = asrc + (size_t)(kt * 64 + cb * CPT) * PPB;
      #pragma unroll
      for (int cc = 0; cc < CPT; cc++) tf[cc] = sp[(size_t)cc * PPB];
      #pragma unroll
      for (int g = 0; g < CPT / 8; g++){
        uint4 wv_;
        wv_.x = (u32)f2bf(tf[g*8+0]) | ((u32)f2bf(tf[g*8+1]) << 16);
        wv_.y = (u32)f2bf(tf[g*8+2]) | ((u32)f2bf(tf[g*8+3]) << 16);
        wv_.z = (u32)f2bf(tf[g*8+4]) | ((u32)f2bf(tf[g*8+5]) << 16);
        wv_.w = (u32)f2bf(tf[g*8+6]) | ((u32)f2bf(tf[g*8+7]) << 16);
        int chunk = cb * (CPT / 8) + g;
        *(uint4*)(ldsA + pi * 128 + ((chunk ^ (pi & 7)) << 4)) = wv_;
      }
    }
    {
      const char* srct = wimg + (size_t)(nt * nK + kt) * (BN * 128);
      #pragma unroll
      for (int it = 0; it < BN / 32; it++){
        int off = t * 16 + it * 4096;
        *(uint4*)(ldsW + off) = *(const uint4*)(srct + off);
      }
    }
    __syncthreads();
    #pragma unroll
    for (int ks = 0; ks < 2; ks++){
      bf16x8 af[4], bfr[4];
      #pragma unroll
      for (int i = 0; i < 4; i++){
        int r = wm * 64 + i * 16 + lr;
        af[i] = *(const bf16x8*)(ldsA + r * 128 + ((((ks << 2) + lg) ^ (r & 7)) << 4));
      }
      #pragma unroll
      for (int j = 0; j < 4; j++){
        int r = wn * 64 + j * 16 + lr;
        bfr[j] = *(const bf16x8*)(ldsW + r * 128 + ((((ks << 2) + lg) ^ (r & 7)) << 4));
      }
      #pragma unroll
      for (int i = 0; i < 4; i++)
        #pragma unroll
        for (int j = 0; j < 4; j++)
          acc[i][j] = __builtin_amdgcn_mfma_f32_16x16x32_bf16(af[i], bfr[j], acc[i][j], 0, 0, 0);
    }
    __syncthreads();
  }

  #pragma unroll
  for (int j = 0; j < 4; j++){
    int nn = n0 + wn * 64 + j * 16 + lr;
    float bs = bias[nn];
    #pragma unroll
    for (int i = 0; i < 4; i++){
      #pragma unroll
      for (int r = 0; r < 4; r++){
        int mm = m0 + wm * 64 + i * 16 + lg * 4 + r;
        float v = acc[i][j][r] + bs;
        if constexpr (EPI == 0){
          *(u16*)((char*)outp + (size_t)mm * ROWB + nn * 2) = f2bf(v);
        } else {
          if (nn < 255){
            int b = mm / PPB, p = mm - b * PPB;
            int a = nn / 85, o = nn - a * 85;
            ((float*)outp)[out_off + ((size_t)(b * 3 + a) * PPB + p) * 85 + o] = v;
          }
        }
      }
    }
  }
}

// ---------------- K2: per 16 coarse px: f1 (MFMA) -> attn (VALU) -> p0 (MFMA) ----------------
__global__ __launch_bounds__(256) void clla_k(const float* __restrict__ x0,
                                              const char* __restrict__ ws,
                                              float* __restrict__ out)
{
  __shared__ char smem[24832];
  char* x0s = smem;                       // [64 fine px][256B] bf16 swizzled; later f1
  char* rs  = smem + 16384;               // [16][256B] r rows swizzled
  char* gs  = smem + 20480;               // [16][256B] g rows swizzled
  float* atts = (float*)(smem + 24576);   // [16][4]

  const u16*  R    = (const u16*)(ws + WS_R);
  const char* wc1i = ws + WS_WC1;
  const char* wdvi = ws + WS_WDV;
  const float* bc1f = (const float*)(ws + WS_BC1);
  const float* b2   = (const float*)(ws + WS_B2);

  const int t = threadIdx.x;
  const int lane = t & 63, wid = t >> 6;
  const int lr = lane & 15, lg = lane >> 4;
  const int blk = blockIdx.x;
  const int b = blk / 400, rem = blk % 400;
  const int h = rem / 5, w0 = (rem % 5) * 16;
  const int c0 = b * 6400 + h * 80 + w0;   // global coarse linear base
  const int pr = h * 80 + w0;              // spatial linear base

  // P1: stage x0 (64 fine px x 128ch) -> x0s ; stage r rows -> rs
  {
    const int f = t & 63, cq = t >> 6;     // fine px = lc*4+n, ch quarter
    const int lc = f >> 2, n = f & 3;
    const float* gp = x0 + ((size_t)b * 128 + cq * 32) * 25600
                    + (size_t)(2 * h + (n >> 1)) * 160 + 2 * (w0 + lc) + (n & 1);
    float tf[32];
    #pragma unroll
    for (int cc = 0; cc < 32; cc++) tf[cc] = gp[(size_t)cc * 25600];
    #pragma unroll
    for (int g = 0; g < 4; g++){
      uint4 wv_;
      wv_.x = (u32)f2bf(tf[g*8+0]) | ((u32)f2bf(tf[g*8+1]) << 16);
      wv_.y = (u32)f2bf(tf[g*8+2]) | ((u32)f2bf(tf[g*8+3]) << 16);
      wv_.z = (u32)f2bf(tf[g*8+4]) | ((u32)f2bf(tf[g*8+5]) << 16);
      wv_.w = (u32)f2bf(tf[g*8+6]) | ((u32)f2bf(tf[g*8+7]) << 16);
      int chunk = cq * 4 + g;
      *(uint4*)(x0s + f * 256 + (((chunk ^ ((f & 7) << 1)) & 15) << 4)) = wv_;
    }
    const int lc2 = t >> 4, c2 = t & 15;
    *(uint4*)(rs + lc2 * 256 + (((c2 ^ ((lc2 & 7) << 1)) & 15) << 4)) =
        *(const uint4*)((const char*)R + (size_t)(c0 + lc2) * 768 + c2 * 16);
  }
  __syncthreads();

  // P2: f1 = Wc1 @ x0 + bc1 via MFMA; wave wid owns m-tile wid (16 rows); overwrite into x0s
  {
    bf16x8 af[4];
    #pragma unroll
    for (int kt = 0; kt < 4; kt++){
      int row = wid * 16 + lr, chunk = kt * 4 + lg;
      af[kt] = *(const bf16x8*)(x0s + row * 256 + (((chunk ^ ((row & 7) << 1)) & 15) << 4));
    }
    f32x4 acc[8];
    #pragma unroll
    for (int j = 0; j < 8; j++) acc[j] = (f32x4){0.f, 0.f, 0.f, 0.f};
    #pragma unroll
    for (int j = 0; j < 8; j++){
      #pragma unroll
      for (int kt = 0; kt < 4; kt++){
        bf16x8 bf = *(const bf16x8*)(wc1i + (j * 16 + lr) * 256 + (kt * 4 + lg) * 16);
        acc[j] = __builtin_amdgcn_mfma_f32_16x16x32_bf16(af[kt], bf, acc[j], 0, 0, 0);
      }
    }
    __syncthreads();
    #pragma unroll
    for (int j = 0; j < 8; j++){
      #pragma unroll
      for (int ri = 0; ri < 4; ri++){
        int px = wid * 16 + lg * 4 + ri;
        int ch = j * 16 + lr;
        float v = acc[j][ri] + bc1f[ch];
        *(u16*)(x0s + px * 256 + ((((ch >> 3) ^ ((px & 7) << 1)) & 15) << 4) + (ch & 7) * 2) = f2bf(v);
      }
    }
  }
  __syncthreads();

  // P3: dots + softmax (validated round-5 logic); dots_n = r . f1_n (consts cancel)
  if (t < 64){
    const int lc = t >> 2;
    const int fr = t;                      // fine row = lc*4+n
    float d = 0.f;
    #pragma unroll
    for (int c = 0; c < 16; c++){
      bf16x8 rv = *(const bf16x8*)(rs  + lc * 256 + (((c ^ ((lc & 7) << 1)) & 15) << 4));
      bf16x8 fv = *(const bf16x8*)(x0s + fr * 256 + (((c ^ ((fr & 7) << 1)) & 15) << 4));
      #pragma unroll
      for (int e = 0; e < 8; e++) d += (float)rv[e] * (float)fv[e];
    }
    float s = d + __shfl_xor(d, 1); s += __shfl_xor(s, 2);
    float irr = 0.5f * s - d;              // 2*mean - dot
    float mx = fmaxf(irr, __shfl_xor(irr, 1)); mx = fmaxf(mx, __shfl_xor(mx, 2));
    float e1 = __expf(irr - mx);
    float den = e1 + __shfl_xor(e1, 1); den += __shfl_xor(den, 2);
    atts[t] = e1 / den;
  }
  __syncthreads();

  // P4: g[lc][ch] = sum_n att*f1 -> gs (bf16 swizzled)
  {
    const int lc = t >> 4, c = t & 15;
    float o[8];
    #pragma unroll
    for (int e = 0; e < 8; e++) o[e] = 0.f;
    #pragma unroll
    for (int n = 0; n < 4; n++){
      float a = atts[lc * 4 + n];
      int fr = lc * 4 + n;
      bf16x8 fv = *(const bf16x8*)(x0s + fr * 256 + (((c ^ ((fr & 7) << 1)) & 15) << 4));
      #pragma unroll
      for (int e = 0; e < 8; e++) o[e] += a * (float)fv[e];
    }
    uint4 wv_;
    wv_.x = (u32)f2bf(o[0]) | ((u32)f2bf(o[1]) << 16);
    wv_.y = (u32)f2bf(o[2]) | ((u32)f2bf(o[3]) << 16);
    wv_.z = (u32)f2bf(o[4]) | ((u32)f2bf(o[5]) << 16);
    wv_.w = (u32)f2bf(o[6]) | ((u32)f2bf(o[7]) << 16);
    *(uint4*)(gs + lc * 256 + (((c ^ ((lc & 7) << 1)) & 15) << 4)) = wv_;
  }
  __syncthreads();

  // P5: p0 = Wdv @ g + h0 + b2 via MFMA (M=16, N=256); wave wid owns n-tiles wid*4..wid*4+3
  {
    bf16x8 af[4];
    #pragma unroll
    for (int kt = 0; kt < 4; kt++){
      int chunk = kt * 4 + lg;
      af[kt] = *(const bf16x8*)(gs + lr * 256 + (((chunk ^ ((lr & 7) << 1)) & 15) << 4));
    }
    #pragma unroll
    for (int jj = 0; jj < 4; jj++){
      int jn = wid * 4 + jj;
      f32x4 acc = (f32x4){0.f, 0.f, 0.f, 0.f};
      #pragma unroll
      for (int kt = 0; kt < 4; kt++){
        bf16x8 bf = *(const bf16x8*)(wdvi + (jn * 16 + lr) * 256 + (kt * 4 + lg) * 16);
        acc = __builtin_amdgcn_mfma_f32_16x16x32_bf16(af[kt], bf, acc, 0, 0, 0);
      }
      int oc = jn * 16 + lr;
      if (oc < 255){
        int a = oc / 85, o = oc - a * 85;
        #pragma unroll
        for (int ri = 0; ri < 4; ri++){
          int px = lg * 4 + ri;
          float v = acc[ri] + bf2f(R[(size_t)(c0 + px) * 384 + 128 + oc]) + b2[oc];
          out[((size_t)(b * 3 + a) * 6400 + pr + px) * 85 + o] = v;
        }
      }
    }
  }
}

extern "C" void kernel_launch(void* const* d_in, const int* in_sizes, int n_in,
                              void* d_out, int out_size, void* d_ws, size_t ws_size,
                              hipStream_t stream)
{
  (void)in_sizes; (void)n_in; (void)out_size; (void)ws_size;
  const float* x0  = (const float*)d_in[0];
  const float* x1  = (const float*)d_in[1];
  const float* x2  = (const float*)d_in[2];
  const float* x3  = (const float*)d_in[3];
  const float* wc1 = (const float*)d_in[4];  const float* bc1 = (const float*)d_in[5];
  const float* wc2 = (const float*)d_in[6];  const float* bc2 = (const float*)d_in[7];
  const float* wq  = (const float*)d_in[8];  const float* bq  = (const float*)d_in[9];
  const float* wk  = (const float*)d_in[10]; (void)d_in[11];
  const float* wv  = (const float*)d_in[12]; const float* bv  = (const float*)d_in[13];
  const float* wdt = (const float*)d_in[14]; const float* bdt = (const float*)d_in[15];
  const float* wm0 = (const float*)d_in[16]; const float* bm0 = (const float*)d_in[17];
  const float* wm1 = (const float*)d_in[18]; const float* bm1 = (const float*)d_in[19];
  char* ws = (char*)d_ws;
  float* out = (float*)d_out;

  prep1_k<<<128, 256, 0, stream>>>(wq, bq, wc2, bc2, ws);
  prep2_k<<<2117, 256, 0, stream>>>(wc1, bc1, wc2, bc2, wk, wv, bv, wdt, bdt,
                                    wm0, bm0, wm1, bm1, ws);
  // R = [r | h0] = A1 @ x1 + c1   (M=51200, K=256, N=384)
  gemm_k<51200, 256, 128, 128, 2, 2, 6400, 256, 0, 768>
      <<<dim3(3, 400), 256, 0, stream>>>(x1, ws + WS_A1, (const float*)(ws + WS_C1), ws + WS_R, 0L);
  // fused f1 + attention + p0
  clla_k<<<3200, 256, 0, stream>>>(x0, ws, out);
  // p1 = head(x2 @ Wm0^T)
  gemm_k<12800, 512, 64, 256, 1, 4, 1600, 512, 2, 0>
      <<<dim3(1, 200), 256, 0, stream>>>(x2, ws + WS_WM0, (const float*)(ws + WS_BM0), out, 13056000L);
  // p2 = head(x3 @ Wm1^T)
  gemm_k<3200, 1024, 64, 256, 1, 4, 400, 1024, 2, 0>
      <<<dim3(1, 50), 256, 0, stream>>>(x3, ws + WS_WM1, (const float*)(ws + WS_BM1), out, 16320000L);
}

// Round 7
// 193.771 us; speedup vs baseline: 5.4729x; 1.0749x over previous
//
#include <hip/hip_runtime.h>

typedef unsigned short u16;
typedef unsigned int   u32;
typedef __bf16 bf16x8 __attribute__((ext_vector_type(8)));
typedef float  f32x4  __attribute__((ext_vector_type(4)));

__device__ __forceinline__ u16 f2bf(float f){
  u32 u = __float_as_uint(f);
  return (u16)((u + 0x7FFFu + ((u >> 16) & 1u)) >> 16);  // RNE
}
__device__ __forceinline__ float bf2f(u16 h){ return __uint_as_float(((u32)h) << 16); }

// ---------------- workspace layout (bytes) ----------------
#define WS_A1    0u          // A1 wimg [384][256] bf16 (BN=128,nK=4)   196608
#define WS_WM0   196608u     // Wm0 wimg [256][512]  (BN=256,nK=8)      262144
#define WS_WM1   458752u     // Wm1 wimg [256][1024] (BN=256,nK=16)     524288
#define WS_WDVC  983040u     // Wdvc = 0.5*Wdet@Wv@Wc1 linear [256][128] bf16  65536
#define WS_C1    1048576u    // c1[384] f32
#define WS_B3    1050112u    // b3[256] f32
#define WS_BM0   1051136u
#define WS_BM1   1052160u
#define WS_T     1053184u    // T[128][256] f32 (Wq@Wc2)
#define WS_U     1184256u    // u[128] f32
#define WS_MR    1184768u    // M_r[128][256] f32 (0.5*Wk^T@T)
#define WS_CR    1315840u    // c_r[128] f32
#define WS_W6    1316352u    // W6[128][128] f32 (Wv@Wc1)
#define WS_U6    1381888u    // u6[128] f32 (Wv*bc1+bv)
#define WS_R     1382400u    // R[51200][384] bf16 = [s(128)|h0(255)|pad]
// end ~40.7 MB

__device__ __forceinline__ size_t wimg_off(int n, int k, int BN, int nK){
  int nt = n / BN, r = n % BN, kt = k >> 6;
  int slot = (((k & 63) >> 3) ^ (r & 7));
  return (size_t)(nt * nK + kt) * (size_t)(BN * 128) + (size_t)r * 128 + (slot << 4) + (k & 7) * 2;
}

// ---------------- prep1: T = Wq@Wc2 [128][256], u = Wq*bc2+bq ----------------
__global__ __launch_bounds__(256) void prep1_k(const float* __restrict__ wq, const float* __restrict__ bq,
                                               const float* __restrict__ wc2, const float* __restrict__ bc2,
                                               char* ws)
{
  float* T = (float*)(ws + WS_T);
  float* u = (float*)(ws + WS_U);
  const int a = blockIdx.x, j = threadIdx.x;
  float s = 0.f;
  for (int c = 0; c < 128; c++) s += wq[a * 128 + c] * wc2[c * 256 + j];
  T[a * 256 + j] = s;
  if (j == 0){
    float su = bq[a];
    for (int c = 0; c < 128; c++) su += wq[a * 128 + c] * bc2[c];
    u[a] = su;
  }
}

// ---------------- prep1b: M_r = 0.5*Wk^T@T, c_r = 0.5*Wk^T@u ; W6 = Wv@Wc1, u6 = Wv*bc1+bv ----
__global__ __launch_bounds__(256) void prep1b_k(const float* __restrict__ wk,
                                                const float* __restrict__ wv,
                                                const float* __restrict__ wc1,
                                                const float* __restrict__ bc1,
                                                const float* __restrict__ bv,
                                                char* ws)
{
  const float* T = (const float*)(ws + WS_T);
  const float* u = (const float*)(ws + WS_U);
  const int blk = blockIdx.x, j = threadIdx.x;
  if (blk < 128){
    int n = blk;
    float s = 0.f;
    for (int a = 0; a < 128; a++) s += wk[a * 128 + n] * T[a * 256 + j];
    ((float*)(ws + WS_MR))[n * 256 + j] = 0.5f * s;
    if (j == 0){
      float sc = 0.f;
      for (int a = 0; a < 128; a++) sc += wk[a * 128 + n] * u[a];
      ((float*)(ws + WS_CR))[n] = 0.5f * sc;
    }
  } else {
    int n = blk - 128;
    if (j < 128){
      float s = 0.f;
      for (int c = 0; c < 128; c++) s += wv[n * 128 + c] * wc1[c * 128 + j];
      ((float*)(ws + WS_W6))[n * 128 + j] = s;
    }
    if (j == 0){
      float s = bv[n];
      for (int c = 0; c < 128; c++) s += wv[n * 128 + c] * bc1[c];
      ((float*)(ws + WS_U6))[n] = s;
    }
  }
}

// ---------------- prep2: weight images + fused biases ----------------
__global__ __launch_bounds__(256) void prep2_k(
    const float* __restrict__ wc1, const float* __restrict__ wc2,
    const float* __restrict__ wdet, const float* __restrict__ bdet,
    const float* __restrict__ wm0, const float* __restrict__ bm0,
    const float* __restrict__ wm1, const float* __restrict__ bm1,
    char* ws)
{
  const float* MR = (const float*)(ws + WS_MR);
  const float* CR = (const float*)(ws + WS_CR);
  const float* W6 = (const float*)(ws + WS_W6);
  const float* U6 = (const float*)(ws + WS_U6);
  int idx = blockIdx.x * 256 + threadIdx.x;
  if (idx < 98304){                       // A1 [384][256]: rows<128 = Wc1^T@M_r ; 128..382 = 0.5*Wdet@Wc2
    int n = idx >> 8, k = idx & 255;
    float s = 0.f;
    if (n < 128){
      for (int c = 0; c < 128; c++) s += wc1[c * 128 + n] * MR[c * 256 + k];
    } else if (n < 383){
      int oc = n - 128;
      for (int c = 0; c < 128; c++) s += wdet[oc * 128 + c] * wc2[c * 256 + k];
      s *= 0.5f;
    }
    *(u16*)(ws + WS_A1 + wimg_off(n, k, 128, 4)) = f2bf(s);
  } else if (idx < 98688){                // c1[384]
    int n = idx - 98304;
    float s = 0.f;
    if (n < 128){
      for (int c = 0; c < 128; c++) s += wc1[c * 128 + n] * CR[c];
    } else if (n < 383){
      int oc = n - 128;
      // 0.5*Wdet@bc2 handled via wc2 path: bc2 folded through h0 const:
      // h0 = 0.5*Wdet@(Wc2 x1 + bc2) -> const part here
      s = 0.f;
    }
    ((float*)(ws + WS_C1))[n] = s;
  } else if (idx < 131456){               // Wdvc [256][128] = 0.5*Wdet@W6
    int id = idx - 98688; int n = id >> 7, k = id & 127;
    float s = 0.f;
    if (n < 255){
      for (int c = 0; c < 128; c++) s += wdet[n * 128 + c] * W6[c * 128 + k];
      s *= 0.5f;
    }
    ((u16*)(ws + WS_WDVC))[n * 128 + k] = f2bf(s);
  } else if (idx < 131712){               // b3[256] = bdet + 0.5*Wdet@u6
    int n = idx - 131456;
    float s = 0.f;
    if (n < 255){
      float ss = 0.f;
      for (int c = 0; c < 128; c++) ss += wdet[n * 128 + c] * U6[c];
      s = bdet[n] + 0.5f * ss;
    }
    ((float*)(ws + WS_B3))[n] = s;
  } else if (idx < 262784){               // Wm0 image [256][512]
    int id = idx - 131712; int n = id >> 9, k = id & 511;
    float s = (n < 255) ? wm0[n * 512 + k] : 0.f;
    *(u16*)(ws + WS_WM0 + wimg_off(n, k, 256, 8)) = f2bf(s);
  } else if (idx < 524928){               // Wm1 image [256][1024]
    int id = idx - 262784; int n = id >> 10, k = id & 1023;
    float s = (n < 255) ? wm1[n * 1024 + k] : 0.f;
    *(u16*)(ws + WS_WM1 + wimg_off(n, k, 256, 16)) = f2bf(s);
  } else if (idx < 525440){               // bm0/bm1
    int id = idx - 524928;
    if (id < 256) ((float*)(ws + WS_BM0))[id] = (id < 255) ? bm0[id] : 0.f;
    else { int n = id - 256; ((float*)(ws + WS_BM1))[n] = (n < 255) ? bm1[n] : 0.f; }
  }
}

// ---------------- prep2b: c1 h0-part needs 0.5*Wdet@bc2 (separate tiny kernel) ----------------
__global__ __launch_bounds__(256) void prep2b_k(const float* __restrict__ wdet,
                                                const float* __restrict__ bc2, char* ws)
{
  int n = threadIdx.x;                    // 0..255
  if (n < 255){
    float s = 0.f;
    for (int c = 0; c < 128; c++) s += wdet[n * 128 + c] * bc2[c];
    ((float*)(ws + WS_C1))[128 + n] = 0.5f * s;
  }
}

// ---------------- generic MFMA GEMM (validated round-6 machinery) ----------------
template<int M, int Kd, int BM, int BN, int WM, int WN, int PPB, int Cin, int EPI, int ROWB>
__global__ __launch_bounds__(256) void gemm_k(const float* __restrict__ Ap, const char* __restrict__ wimg,
                                              const float* __restrict__ bias, void* __restrict__ outp, long out_off)
{
  constexpr int nK  = Kd / 64;
  constexpr int TPP = 256 / BM;
  constexpr int CPT = 64 / TPP;
  __shared__ char lds[BM * 128 + BN * 128];
  char* ldsA = lds;
  char* ldsW = lds + BM * 128;
  const int t = threadIdx.x;
  const int lane = t & 63;
  const int wid = t >> 6;
  const int wm = wid / WN, wn = wid % WN;
  const int nt = blockIdx.x, mt = blockIdx.y;
  const int m0 = mt * BM, n0 = nt * BN;
  const int lr = lane & 15, lg = lane >> 4;
  f32x4 acc[4][4] = {};

  const int pi = t % BM, cb = t / BM;
  const float* asrc;
  {
    int mg = m0 + pi; int b = mg / PPB; int p = mg - b * PPB;
    asrc = Ap + (size_t)b * Cin * PPB + p;
  }

  for (int kt = 0; kt < nK; kt++){
    {
      float tf[CPT];
      const float* sp = asrc + (size_t)(kt * 64 + cb * CPT) * PPB;
      #pragma unroll
      for (int cc = 0; cc < CPT; cc++) tf[cc] = sp[(size_t)cc * PPB];
      #pragma unroll
      for (int g = 0; g < CPT / 8; g++){
        uint4 wv_;
        wv_.x = (u32)f2bf(tf[g*8+0]) | ((u32)f2bf(tf[g*8+1]) << 16);
        wv_.y = (u32)f2bf(tf[g*8+2]) | ((u32)f2bf(tf[g*8+3]) << 16);
        wv_.z = (u32)f2bf(tf[g*8+4]) | ((u32)f2bf(tf[g*8+5]) << 16);
        wv_.w = (u32)f2bf(tf[g*8+6]) | ((u32)f2bf(tf[g*8+7]) << 16);
        int chunk = cb * (CPT / 8) + g;
        *(uint4*)(ldsA + pi * 128 + ((chunk ^ (pi & 7)) << 4)) = wv_;
      }
    }
    {
      const char* srct = wimg + (size_t)(nt * nK + kt) * (BN * 128);
      #pragma unroll
      for (int it = 0; it < BN / 32; it++){
        int off = t * 16 + it * 4096;
        *(uint4*)(ldsW + off) = *(const uint4*)(srct + off);
      }
    }
    __syncthreads();
    #pragma unroll
    for (int ks = 0; ks < 2; ks++){
      bf16x8 af[4], bfr[4];
      #pragma unroll
      for (int i = 0; i < 4; i++){
        int r = wm * 64 + i * 16 + lr;
        af[i] = *(const bf16x8*)(ldsA + r * 128 + ((((ks << 2) + lg) ^ (r & 7)) << 4));
      }
      #pragma unroll
      for (int j = 0; j < 4; j++){
        int r = wn * 64 + j * 16 + lr;
        bfr[j] = *(const bf16x8*)(ldsW + r * 128 + ((((ks << 2) + lg) ^ (r & 7)) << 4));
      }
      #pragma unroll
      for (int i = 0; i < 4; i++)
        #pragma unroll
        for (int j = 0; j < 4; j++)
          acc[i][j] = __builtin_amdgcn_mfma_f32_16x16x32_bf16(af[i], bfr[j], acc[i][j], 0, 0, 0);
    }
    __syncthreads();
  }

  #pragma unroll
  for (int j = 0; j < 4; j++){
    int nn = n0 + wn * 64 + j * 16 + lr;
    float bs = bias[nn];
    #pragma unroll
    for (int i = 0; i < 4; i++){
      #pragma unroll
      for (int r = 0; r < 4; r++){
        int mm = m0 + wm * 64 + i * 16 + lg * 4 + r;
        float v = acc[i][j][r] + bs;
        if constexpr (EPI == 0){
          *(u16*)((char*)outp + (size_t)mm * ROWB + nn * 2) = f2bf(v);
        } else {
          if (nn < 255){
            int b = mm / PPB, p = mm - b * PPB;
            int a = nn / 85, o = nn - a * 85;
            ((float*)outp)[out_off + ((size_t)(b * 3 + a) * PPB + p) * 85 + o] = v;
          }
        }
      }
    }
  }
}

// ---------------- clla: dots from raw x0, softmax, y, p0 MFMA ----------------
__global__ __launch_bounds__(256) void clla_k(const float* __restrict__ x0,
                                              const char* __restrict__ ws,
                                              float* __restrict__ out)
{
  __shared__ char smem[24832];
  char* x0s = smem;                       // [64 fine px][256B] bf16 swizzled
  char* rs  = smem + 16384;               // [16][256B] s rows swizzled
  char* gs  = smem + 20480;               // [16][256B] y rows swizzled
  float* atts = (float*)(smem + 24576);   // [16][4]

  const u16*  R    = (const u16*)(ws + WS_R);
  const char* Rb   = ws + WS_R;
  const char* wdvi = ws + WS_WDVC;
  const float* b3  = (const float*)(ws + WS_B3);

  const int t = threadIdx.x;
  const int lane = t & 63, wid = t >> 6;
  const int lr = lane & 15, lg = lane >> 4;
  const int blk = blockIdx.x;
  const int b = blk / 400, rem = blk % 400;
  const int h = rem / 5, w0 = (rem % 5) * 16;
  const int c0 = b * 6400 + h * 80 + w0;
  const int pr = h * 80 + w0;

  // P1: stage x0 (64 fine px x 128ch) -> bf16 swizzled ; stage s rows -> rs
  {
    const int f = t & 63, cq = t >> 6;
    const int lc = f >> 2, n = f & 3;
    const float* gp = x0 + ((size_t)b * 128 + cq * 32) * 25600
                    + (size_t)(2 * h + (n >> 1)) * 160 + 2 * (w0 + lc) + (n & 1);
    float tf[32];
    #pragma unroll
    for (int cc = 0; cc < 32; cc++) tf[cc] = gp[(size_t)cc * 25600];
    #pragma unroll
    for (int g = 0; g < 4; g++){
      uint4 wv_;
      wv_.x = (u32)f2bf(tf[g*8+0]) | ((u32)f2bf(tf[g*8+1]) << 16);
      wv_.y = (u32)f2bf(tf[g*8+2]) | ((u32)f2bf(tf[g*8+3]) << 16);
      wv_.z = (u32)f2bf(tf[g*8+4]) | ((u32)f2bf(tf[g*8+5]) << 16);
      wv_.w = (u32)f2bf(tf[g*8+6]) | ((u32)f2bf(tf[g*8+7]) << 16);
      int chunk = cq * 4 + g;
      *(uint4*)(x0s + f * 256 + (((chunk ^ ((f & 7) << 1)) & 15) << 4)) = wv_;
    }
    const int lc2 = t >> 4, c2 = t & 15;
    *(uint4*)(rs + lc2 * 256 + (((c2 ^ ((lc2 & 7) << 1)) & 15) << 4)) =
        *(const uint4*)(Rb + (size_t)(c0 + lc2) * 768 + c2 * 16);
  }
  __syncthreads();

  // P2: dots + softmax, all 256 threads: t = [px(4b)][n(2b)][cq(2b)]
  {
    const int px = t >> 4, n = (t >> 2) & 3, cq = t & 3;
    const int fr = px * 4 + n;
    float d = 0.f;
    #pragma unroll
    for (int g = 0; g < 4; g++){
      int c = cq * 4 + g;
      bf16x8 rv = *(const bf16x8*)(rs  + px * 256 + (((c ^ ((px & 7) << 1)) & 15) << 4));
      bf16x8 fv = *(const bf16x8*)(x0s + fr * 256 + (((c ^ ((fr & 7) << 1)) & 15) << 4));
      #pragma unroll
      for (int e = 0; e < 8; e++) d += (float)rv[e] * (float)fv[e];
    }
    d += __shfl_xor(d, 1); d += __shfl_xor(d, 2);      // full dot on all cq lanes
    float s4 = d + __shfl_xor(d, 4); s4 += __shfl_xor(s4, 8);
    float irr = 0.5f * s4 - d;                          // 2*mean - dot
    float mx = fmaxf(irr, __shfl_xor(irr, 4)); mx = fmaxf(mx, __shfl_xor(mx, 8));
    float e1 = __expf(irr - mx);
    float den = e1 + __shfl_xor(e1, 4); den += __shfl_xor(den, 8);
    if (cq == 0) atts[px * 4 + n] = e1 / den;
  }
  __syncthreads();

  // P3: y = sum_n att*x0_n -> gs bf16 swizzled (t = px*16 + cp)
  {
    const int px = t >> 4, cp = t & 15;
    float o[8];
    #pragma unroll
    for (int e = 0; e < 8; e++) o[e] = 0.f;
    #pragma unroll
    for (int n = 0; n < 4; n++){
      float a = atts[px * 4 + n];
      int fr = px * 4 + n;
      bf16x8 fv = *(const bf16x8*)(x0s + fr * 256 + (((cp ^ ((fr & 7) << 1)) & 15) << 4));
      #pragma unroll
      for (int e = 0; e < 8; e++) o[e] += a * (float)fv[e];
    }
    uint4 wv_;
    wv_.x = (u32)f2bf(o[0]) | ((u32)f2bf(o[1]) << 16);
    wv_.y = (u32)f2bf(o[2]) | ((u32)f2bf(o[3]) << 16);
    wv_.z = (u32)f2bf(o[4]) | ((u32)f2bf(o[5]) << 16);
    wv_.w = (u32)f2bf(o[6]) | ((u32)f2bf(o[7]) << 16);
    *(uint4*)(gs + px * 256 + (((cp ^ ((px & 7) << 1)) & 15) << 4)) = wv_;
  }
  __syncthreads();

  // P4: p0 = Wdvc @ y + h0 + b3 via MFMA (M=16, N=256)
  {
    bf16x8 af[4];
    #pragma unroll
    for (int kt = 0; kt < 4; kt++){
      int chunk = kt * 4 + lg;
      af[kt] = *(const bf16x8*)(gs + lr * 256 + (((chunk ^ ((lr & 7) << 1)) & 15) << 4));
    }
    #pragma unroll
    for (int jj = 0; jj < 4; jj++){
      int jn = wid * 4 + jj;
      f32x4 acc = (f32x4){0.f, 0.f, 0.f, 0.f};
      #pragma unroll
      for (int kt = 0; kt < 4; kt++){
        bf16x8 bf = *(const bf16x8*)(wdvi + (jn * 16 + lr) * 256 + (kt * 4 + lg) * 16);
        acc = __builtin_amdgcn_mfma_f32_16x16x32_bf16(af[kt], bf, acc, 0, 0, 0);
      }
      int oc = jn * 16 + lr;
      if (oc < 255){
        int a = oc / 85, o = oc - a * 85;
        #pragma unroll
        for (int ri = 0; ri < 4; ri++){
          int px = lg * 4 + ri;
          float v = acc[ri] + bf2f(R[(size_t)(c0 + px) * 384 + 128 + oc]) + b3[oc];
          out[((size_t)(b * 3 + a) * 6400 + pr + px) * 85 + o] = v;
        }
      }
    }
  }
}

extern "C" void kernel_launch(void* const* d_in, const int* in_sizes, int n_in,
                              void* d_out, int out_size, void* d_ws, size_t ws_size,
                              hipStream_t stream)
{
  (void)in_sizes; (void)n_in; (void)out_size; (void)ws_size;
  const float* x0  = (const float*)d_in[0];
  const float* x1  = (const float*)d_in[1];
  const float* x2  = (const float*)d_in[2];
  const float* x3  = (const float*)d_in[3];
  const float* wc1 = (const float*)d_in[4];  const float* bc1 = (const float*)d_in[5];
  const float* wc2 = (const float*)d_in[6];  const float* bc2 = (const float*)d_in[7];
  const float* wq  = (const float*)d_in[8];  const float* bq  = (const float*)d_in[9];
  const float* wk  = (const float*)d_in[10];
  const float* wv  = (const float*)d_in[12]; const float* bv  = (const float*)d_in[13];
  const float* wdt = (const float*)d_in[14]; const float* bdt = (const float*)d_in[15];
  const float* wm0 = (const float*)d_in[16]; const float* bm0 = (const float*)d_in[17];
  const float* wm1 = (const float*)d_in[18]; const float* bm1 = (const float*)d_in[19];
  char* ws = (char*)d_ws;
  float* out = (float*)d_out;

  prep1_k<<<128, 256, 0, stream>>>(wq, bq, wc2, bc2, ws);
  prep1b_k<<<256, 256, 0, stream>>>(wk, wv, wc1, bc1, bv, ws);
  prep2_k<<<2053, 256, 0, stream>>>(wc1, wc2, wdt, bdt, wm0, bm0, wm1, bm1, ws);
  prep2b_k<<<1, 256, 0, stream>>>(wdt, bc2, ws);
  // R = [s | h0] = A1 @ x1 + c1   (M=51200, K=256, N=384)
  gemm_k<51200, 256, 128, 128, 2, 2, 6400, 256, 0, 768>
      <<<dim3(3, 400), 256, 0, stream>>>(x1, ws + WS_A1, (const float*)(ws + WS_C1), ws + WS_R, 0L);
  // fused dots/softmax/y/p0
  clla_k<<<3200, 256, 0, stream>>>(x0, ws, out);
  // p1 = head(x2 @ Wm0^T)
  gemm_k<12800, 512, 64, 256, 1, 4, 1600, 512, 2, 0>
      <<<dim3(1, 200), 256, 0, stream>>>(x2, ws + WS_WM0, (const float*)(ws + WS_BM0), out, 13056000L);
  // p2 = head(x3 @ Wm1^T)
  gemm_k<3200, 1024, 64, 256, 1, 4, 400, 1024, 2, 0>
      <<<dim3(1, 50), 256, 0, stream>>>(x3, ws + WS_WM1, (const float*)(ws + WS_BM1), out, 16320000L);
}